// Round 12
// baseline (411.269 us; speedup 1.0000x reference)
//
#include <hip/hip_runtime.h>

static constexpr int   Bn      = 32;
static constexpr int   Tn      = 2000;
static constexpr int   Hn      = 512;
static constexpr int   Ln      = 256;     // max_label_len
static constexpr float kThresh = 0.95f;
static constexpr int   TCHUNK  = 40;
static constexpr int   NTCH    = Tn / TCHUNK;   // 50
static constexpr int   NPROD   = Bn;            // 32 producer blocks (first)
static constexpr int   SLOTS_PER_BLK = 8;       // consumer: 8 slots/block
static constexpr int   NCONS   = Bn * (Ln / SLOTS_PER_BLK);  // 1024
static constexpr unsigned DONE = 1u << 16;
static constexpr int   FDSTRIDE = 16;           // pad fires_done to 64 B/row

// ---------------------------------------------------------------------------
// Fused producer-consumer CIF. R11 diagnostic: K1 (serial scan) = 38.7 us,
// K2+ov = 38.8 us, fully serialized -> overlap them. R9's 10x regression is
// explained by its counters (VGPR_Count=12: the alpha double-buffer spilled
// to scratch, putting ~100+ cyc of scratch traffic INSIDE the serial chain).
// Fixes here:
//   1. __launch_bounds__(256, 1): min 1 wave/EU -> VGPR budget ~512; the
//      producer's 80-reg prefetch buffers stay in registers.
//   2. Only 1024 consumer blocks (8 slots each), ~fully resident; lane-0
//      spin with s_sleep(32) => ~1 probe per ~850 cyc per waiting wave, so
//      consumers steal essentially no issue slots from producer CUs.
//   3. Producer wave runs at s_setprio(3).
// Replay safety by idempotence: tf/cwrem are rewritten with IDENTICAL values
// every call (deterministic), so stale L1/L2 lines are harmless; only the
// 2 KB flag array must be zeroed per call (hipMemsetAsync, in-graph).
// Memory ordering: producer bumps fires_done[b] with an agent-scope RELEASE
// store after each 40-step chunk (orders the table stores before it);
// consumers use agent-scope ACQUIRE loads (proven bit-exact in R9).
// ---------------------------------------------------------------------------
__global__ __launch_bounds__(256, 1) void cif_fused_kernel(
    const float* __restrict__ hidden,
    const float* __restrict__ alphas,
    unsigned* __restrict__ fires_done,  // [Bn*FDSTRIDE]
    int*      __restrict__ tf,          // [Bn][Ln] fire timestep
    float2*   __restrict__ cwrem,       // [Bn][Ln] (closing w, remainder w)
    float*    __restrict__ out) {
  if (blockIdx.x < NPROD) {
    // ---------------- producer: serial scan for row b ----------------
    if (threadIdx.x >= 64) return;      // one wave; waves 1..3 exit
    __builtin_amdgcn_s_setprio(3);
    const int b    = blockIdx.x;
    const int lane = threadIdx.x;
    const float4* __restrict__ arow =
        reinterpret_cast<const float4*>(alphas + (size_t)b * Tn);
    constexpr int CV = TCHUNK / 4;      // 10 float4 per chunk

    float integrate = 0.0f;
    int   fc        = 0;

    float4 cur[CV], nxt[CV];
#pragma unroll
    for (int i = 0; i < CV; ++i) cur[i] = arow[i];

    for (int c = 0; c < NTCH; ++c) {
      if (c + 1 < NTCH) {
#pragma unroll
        for (int i = 0; i < CV; ++i) nxt[i] = arow[(c + 1) * CV + i];
      }
      const int tbase = c * TCHUNK;
#pragma unroll
      for (int i = 0; i < CV; ++i) {
        const float a4[4] = {cur[i].x, cur[i].y, cur[i].z, cur[i].w};
#pragma unroll
        for (int j = 0; j < 4; ++j) {
          const float a     = a4[j];
          const float integ = integrate + a;      // reference op order
          const bool  fire  = integ > kThresh;    // wave-uniform branch
          if (fire) {
            if (lane == 0 && fc < Ln) {           // ~1 fire per 8 steps
              const float cw = 1.0f - integrate;  // dist_completion
              tf   [b * Ln + fc] = tbase + i * 4 + j;
              cwrem[b * Ln + fc] = make_float2(cw, a - cw);
            }
          }
          integrate = fire ? (integ - 1.0f) : integ;  // proven select form
          fc += fire ? 1 : 0;
        }
      }
#pragma unroll
      for (int i = 0; i < CV; ++i) cur[i] = nxt[i];
      if (lane == 0)   // release: table stores visible before counter bump
        __hip_atomic_store(&fires_done[b * FDSTRIDE], (unsigned)fc,
                           __ATOMIC_RELEASE, __HIP_MEMORY_SCOPE_AGENT);
    }
    if (lane == 0)
      __hip_atomic_store(&fires_done[b * FDSTRIDE], (unsigned)fc | DONE,
                         __ATOMIC_RELEASE, __HIP_MEMORY_SCOPE_AGENT);
    return;
  }

  // ---------------- consumer: 8 output slots for row b ----------------
  const int c   = blockIdx.x - NPROD;   // 0..1023
  const int b   = c & (Bn - 1);
  const int g   = c >> 5;               // slot group 0..31
  const int col = threadIdx.x * 2;      // float2 over H=512

  const float* __restrict__ hbase = hidden + (size_t)b * Tn * Hn + col;
  const float* __restrict__ arow  = alphas + (size_t)b * Tn;

  __shared__ unsigned s_v;

  for (int k = 0; k < SLOTS_PER_BLK; ++k) {
    const int s = g * SLOTS_PER_BLK + k;

    if (threadIdx.x == 0) {
      unsigned v;
      for (;;) {
        v = __hip_atomic_load(&fires_done[b * FDSTRIDE], __ATOMIC_ACQUIRE,
                              __HIP_MEMORY_SCOPE_AGENT);
        if ((v & 0xFFFFu) >= (unsigned)(s + 1) || (v & DONE)) break;
        __builtin_amdgcn_s_sleep(32);   // ~2k clocks: near-zero issue theft
      }
      s_v = v;
    }
    __syncthreads();
    const int fc_now = (int)(s_v & 0xFFFFu);

    float* __restrict__ o = out + ((size_t)b * Ln + s) * Hn + col;

    if (fc_now < s + 1) {               // DONE and slot never fires: zeros
      *reinterpret_cast<float2*>(o) = make_float2(0.f, 0.f);
    } else {
      const int t_hi   = tf[b * Ln + s];
      const int t_prev = (s > 0) ? tf[b * Ln + s - 1] : -1;

      float2 acc = make_float2(0.f, 0.f);
      if (s > 0) {                      // opening: frame = rem * h[t_prev]
        const float r  = cwrem[b * Ln + s - 1].y;
        const float2 h =
            *reinterpret_cast<const float2*>(hbase + (size_t)t_prev * Hn);
        acc.x = r * h.x; acc.y = r * h.y;
      }
      for (int t = t_prev + 1; t < t_hi; ++t) {  // interior: raw alpha
        const float a  = arow[t];
        const float2 h =
            *reinterpret_cast<const float2*>(hbase + (size_t)t * Hn);
        acc.x += a * h.x; acc.y += a * h.y;
      }
      {                                 // closing: dist_completion
        const float cw = cwrem[b * Ln + s].x;
        const float2 h =
            *reinterpret_cast<const float2*>(hbase + (size_t)t_hi * Hn);
        acc.x += cw * h.x; acc.y += cw * h.y;
      }
      *reinterpret_cast<float2*>(o) = acc;
    }
    __syncthreads();                    // WAR: s_v rewritten next iteration
  }
}

extern "C" void kernel_launch(void* const* d_in, const int* in_sizes, int n_in,
                              void* d_out, int out_size, void* d_ws, size_t ws_size,
                              hipStream_t stream) {
  const float* hidden = (const float*)d_in[0];
  const float* alphas = (const float*)d_in[1];
  float* out = (float*)d_out;

  // ws layout: fires_done[Bn*FDSTRIDE] u32 (2 KB, memset each call)
  //          | tf[B][Ln] i32 (32 KB) | cwrem[B][Ln] float2 (64 KB)
  unsigned* fires_done = (unsigned*)d_ws;
  int*      tf         = (int*)(fires_done + (size_t)Bn * FDSTRIDE);
  float2*   cwrem      = (float2*)(tf + (size_t)Bn * Ln);

  // Progress flags must start at 0 every call (table itself is idempotent).
  hipMemsetAsync(fires_done, 0, (size_t)Bn * FDSTRIDE * sizeof(unsigned),
                 stream);

  const int nblocks = NPROD + NCONS;    // 32 producers + 1024 consumers
  cif_fused_kernel<<<nblocks, 256, 0, stream>>>(hidden, alphas, fires_done,
                                                tf, cwrem, out);
}

// Round 13
// 179.955 us; speedup vs baseline: 2.2854x; 2.2854x over previous
//
#include <hip/hip_runtime.h>

static constexpr int   Bn      = 32;
static constexpr int   Tn      = 2000;
static constexpr int   Hn      = 512;
static constexpr int   Ln      = 256;     // max_label_len
static constexpr float kThresh = 0.95f;
static constexpr int   TCHUNK  = 40;
static constexpr int   NTCH    = Tn / TCHUNK;   // 50

// ---------------------------------------------------------------------------
// K1: ONE block; lane b runs row b's serial integrate-and-fire chain. All 32
// row-chains advance in lockstep in a single wave, so the whole scan costs
// one dependent add->cmp->cndmask chain (~12-15 cyc/step) instead of R10's
// per-row kernel whose snapshot+replay structure measured 46 cyc/step
// (R11 diagnostic: 38.7 us). Fire events go to an LDS fire table via
// ds_write (lgkm-ordered -- does NOT trigger the vmcnt(0)-in-chain drain
// that killed R2-R6 global-store variants), flushed coalesced at the end.
// Lane b's alpha row is contiguous -> per-lane float4 loads, double-buffered
// one chunk ahead. Lanes 32-63 mirror lanes 0-31 (same chain, stores
// suppressed) to fill the wave. Bit-exact: per-row f32 op order identical to
// the reference scan (proven absmax 0.0 in R8-R11).
// ---------------------------------------------------------------------------
__global__ __launch_bounds__(64, 1) void cif_scan32_kernel(
    const float* __restrict__ alphas,
    int*   __restrict__ tf,     // [Bn][Ln] fire timestep
    float* __restrict__ cwv,    // [Bn][Ln] closing weight (dist_completion)
    float* __restrict__ remv,   // [Bn][Ln] remainder weight (opens next seg)
    int*   __restrict__ fcnt) { // [Bn]
  const int lane = threadIdx.x;
  const int b    = lane & (Bn - 1);          // lanes 32-63 mirror rows
  const bool owner = (lane < Bn);

  __shared__ __align__(16) int   tf_lds[Bn][Ln];
  __shared__ __align__(16) float cw_lds[Bn][Ln];
  __shared__ __align__(16) float rm_lds[Bn][Ln];

  // Zero-init LDS (vectorized) so the copy-out is deterministic everywhere.
  {
    int4*   tz = reinterpret_cast<int4*>(&tf_lds[0][0]);
    float4* cz = reinterpret_cast<float4*>(&cw_lds[0][0]);
    float4* rz = reinterpret_cast<float4*>(&rm_lds[0][0]);
    const float4 z4 = make_float4(0.f, 0.f, 0.f, 0.f);
    for (int i = lane; i < Bn * Ln / 4; i += 64) {
      tz[i] = make_int4(0, 0, 0, 0);
      cz[i] = z4;
      rz[i] = z4;
    }
  }
  __syncthreads();

  const float4* __restrict__ arow =
      reinterpret_cast<const float4*>(alphas + (size_t)b * Tn);
  constexpr int CV = TCHUNK / 4;             // 10 float4 per chunk

  float I  = 0.0f;                           // integrate
  int   fc = 0;

  float4 cur[CV], nxt[CV];
#pragma unroll
  for (int i = 0; i < CV; ++i) cur[i] = arow[i];

  for (int c = 0; c < NTCH; ++c) {
    if (c + 1 < NTCH) {
#pragma unroll
      for (int i = 0; i < CV; ++i) nxt[i] = arow[(c + 1) * CV + i];
    }
    const int tbase = c * TCHUNK;
#pragma unroll
    for (int i = 0; i < CV; ++i) {
      const float a4[4] = {cur[i].x, cur[i].y, cur[i].z, cur[i].w};
#pragma unroll
      for (int j = 0; j < 4; ++j) {
        const float a     = a4[j];
        const float integ = I + a;           // reference op order
        const bool  fire  = integ > kThresh; // per-lane divergent now
        if (fire && owner && fc < Ln) {      // LDS only: no vmcnt in chain
          const float cw  = 1.0f - I;        // dist_completion
          tf_lds[b][fc] = tbase + i * 4 + j;
          cw_lds[b][fc] = cw;
          rm_lds[b][fc] = a - cw;            // remainds
        }
        I  = fire ? (integ - 1.0f) : integ;  // proven select form
        fc += fire ? 1 : 0;
      }
    }
#pragma unroll
    for (int i = 0; i < CV; ++i) cur[i] = nxt[i];
  }
  if (owner) fcnt[b] = fc;
  __syncthreads();

  // Coalesced bulk flush LDS -> global (3 x 32 KB).
  {
    const int4*   ts = reinterpret_cast<const int4*>(&tf_lds[0][0]);
    const float4* cs = reinterpret_cast<const float4*>(&cw_lds[0][0]);
    const float4* rs = reinterpret_cast<const float4*>(&rm_lds[0][0]);
    int4*   tg = reinterpret_cast<int4*>(tf);
    float4* cg = reinterpret_cast<float4*>(cwv);
    float4* rg = reinterpret_cast<float4*>(remv);
    for (int i = lane; i < Bn * Ln / 4; i += 64) {
      tg[i] = ts[i];
      cg[i] = cs[i];
      rg[i] = rs[i];
    }
  }
}

// ---------------------------------------------------------------------------
// K2 (unchanged from R10, proven bit-exact): block (s, b) EXCLUSIVELY owns
// out[b][s]. Segment s spans (t_prev, t_hi]: rem[s-1]*h[t_prev] + raw-alpha
// interior + cw[s]*h[t_hi], ascending t. Plain float4 stores, no atomics;
// s >= min(fcnt,Ln) slots store zeros -> no pre-zero pass needed.
// ---------------------------------------------------------------------------
__global__ __launch_bounds__(128) void cif_seg_accum_kernel(
    const float* __restrict__ hidden,
    const float* __restrict__ alphas,
    const int*   __restrict__ tf,
    const float* __restrict__ cwv,
    const float* __restrict__ remv,
    const int*   __restrict__ fcnt,
    float* __restrict__ out) {
  const int s   = blockIdx.x;          // 0..Ln-1
  const int b   = blockIdx.y;          // 0..Bn-1
  const int col = threadIdx.x * 4;

  const int fb    = fcnt[b];
  const int limit = fb < Ln ? fb : Ln;

  float* __restrict__ o = out + ((size_t)b * Ln + s) * Hn + col;

  if (s >= limit) {                    // never-fired slot: emit zeros
    *reinterpret_cast<float4*>(o) = make_float4(0.f, 0.f, 0.f, 0.f);
    return;
  }

  const int t_hi   = tf[b * Ln + s];
  const int t_prev = (s > 0) ? tf[b * Ln + s - 1] : -1;

  const float* __restrict__ hbase = hidden + (size_t)b * Tn * Hn + col;
  const float* __restrict__ arow  = alphas + (size_t)b * Tn;

  float4 acc = make_float4(0.f, 0.f, 0.f, 0.f);

  if (s > 0) {                         // opening: frame = rem * h[t_prev]
    const float r  = remv[b * Ln + s - 1];
    const float4 h = *reinterpret_cast<const float4*>(hbase + (size_t)t_prev * Hn);
    acc.x = r * h.x; acc.y = r * h.y; acc.z = r * h.z; acc.w = r * h.w;
  }
  for (int t = t_prev + 1; t < t_hi; ++t) {   // interior: weight = raw alpha
    const float a  = arow[t];
    const float4 h = *reinterpret_cast<const float4*>(hbase + (size_t)t * Hn);
    acc.x += a * h.x; acc.y += a * h.y; acc.z += a * h.z; acc.w += a * h.w;
  }
  {                                    // closing: weight = dist_completion
    const float c  = cwv[b * Ln + s];
    const float4 h = *reinterpret_cast<const float4*>(hbase + (size_t)t_hi * Hn);
    acc.x += c * h.x; acc.y += c * h.y; acc.z += c * h.z; acc.w += c * h.w;
  }
  *reinterpret_cast<float4*>(o) = acc;
}

extern "C" void kernel_launch(void* const* d_in, const int* in_sizes, int n_in,
                              void* d_out, int out_size, void* d_ws, size_t ws_size,
                              hipStream_t stream) {
  const float* hidden = (const float*)d_in[0];
  const float* alphas = (const float*)d_in[1];
  float* out = (float*)d_out;

  // ws layout: tf[B][Ln] i32 (32 KB) | cw[B][Ln] f32 | rem[B][Ln] f32 | fcnt[B]
  int*   tf   = (int*)d_ws;
  float* cwv  = (float*)(tf + (size_t)Bn * Ln);
  float* remv = cwv + (size_t)Bn * Ln;
  int*   fcnt = (int*)(remv + (size_t)Bn * Ln);

  cif_scan32_kernel<<<1, 64, 0, stream>>>(alphas, tf, cwv, remv, fcnt);

  dim3 grid(Ln, Bn);   // 8192 independent blocks, one per output slot
  cif_seg_accum_kernel<<<grid, 128, 0, stream>>>(hidden, alphas, tf, cwv,
                                                 remv, fcnt, out);
}